// Round 17
// baseline (297.039 us; speedup 1.0000x reference)
//
#include <hip/hip_runtime.h>

#define T_   256
#define F_   32
#define NBB  16     // full 16-wide fragments
#define TPB  768    // 12 waves: 0-7 L1-role (2 tiles), 8-11 L2-role (2 tiles)
#define IMW  104
#define PR1  260    // pre1 row stride (f32), 16B-aligned
#define PR2  132

typedef __attribute__((ext_vector_type(8))) short bf16x8;
typedef __attribute__((ext_vector_type(4))) float f32x4;

#define K1f  (-1.44269504f)   // -log2(e)   : sigmoid gates
#define K2f  (-2.88539008f)   // -2*log2(e) : tanh gate & tanh(c)

__device__ __forceinline__ unsigned short bf16_rne(float x){
    unsigned u = __float_as_uint(x);
    u += 0x7FFF + ((u >> 16) & 1);
    return (unsigned short)(u >> 16);
}
__device__ __forceinline__ void bf16_split(float x, unsigned short& h, unsigned short& l){
    h = bf16_rne(x);
    float xr = __uint_as_float(((unsigned)h) << 16);
    l = bf16_rne(x - xr);
}
__device__ __forceinline__ void make_frags_s(const float* __restrict__ p8, float s,
                                             bf16x8& fh, bf16x8& fl){
    #pragma unroll
    for (int e = 0; e < 8; ++e){
        unsigned short h, l; bf16_split(s * p8[e], h, l);
        fh[e] = (short)h; fl[e] = (short)l;
    }
}
__device__ __forceinline__ float sigm_pre(float p){   // p = -log2e*x
    return __builtin_amdgcn_rcpf(1.f + __builtin_amdgcn_exp2f(p));
}
__device__ __forceinline__ float tanh_pre(float p){   // p = -2log2e*x
    return fmaf(2.f, __builtin_amdgcn_rcpf(1.f + __builtin_amdgcn_exp2f(p)), -1.f);
}
__device__ __forceinline__ float unit_combine(float gi, float gf, float gg, float go, float& c){
    const float i_ = sigm_pre(gi);
    const float f_ = sigm_pre(gf);
    const float g_ = tanh_pre(gg);
    const float o_ = sigm_pre(go);
    c = fmaf(f_, c, i_ * g_);
    return o_ * tanh_pre(K2f * c);
}

#define MFMA(A,B,C) __builtin_amdgcn_mfma_f32_16x16x32_bf16((A),(B),(C),0,0,0)

// LDS-visibility barrier WITHOUT vmcnt drain (x-loads stay in flight).
__device__ __forceinline__ void step_barrier(){
    asm volatile("s_waitcnt lgkmcnt(0)" ::: "memory");
    __builtin_amdgcn_s_barrier();
}

// (768,3): 12 waves = 3/SIMD. r16 measured: VGPR=64 + AGPR-resident weights, no spill.
__global__ __launch_bounds__(TPB, 3) void lstm_mfma(
    const float* __restrict__ x,      // [4096,256,32]
    const float* __restrict__ W_ih1,  // [256,32]
    const float* __restrict__ W_hh1,  // [256,64]
    const float* __restrict__ b_ih1,  // [256]
    const float* __restrict__ b_hh1,  // [256]
    const float* __restrict__ W_ih2,  // [128,64]
    const float* __restrict__ W_hh2,  // [128,32]
    const float* __restrict__ b_ih2,  // [128]
    const float* __restrict__ b_hh2,  // [128]
    const float* __restrict__ W_fc1,  // [16,32]
    const float* __restrict__ b_fc1,  // [16]
    const float* __restrict__ W_fc2,  // [1,16]
    const float* __restrict__ b_fc2,  // [1]
    float* __restrict__ out)          // [4096]
{
    const int tid  = threadIdx.x;
    const int lane = tid & 63;
    const int wid  = tid >> 6;        // 0..11
    const int bb   = lane & 15;       // fragment col = batch
    const int kg   = (lane >> 4) & 3; // k-group of 8
    const int b0   = blockIdx.x * NBB;

    __shared__ __align__(16) unsigned short i1h[2][NBB][IMW], i1l[2][NBB][IMW];
    __shared__ __align__(16) unsigned short i2h[2][NBB][IMW], i2l[2][NBB][IMW];
    __shared__ __align__(16) float pre1[NBB * PR1];
    __shared__ __align__(16) float pre2[NBB * PR2];
    __shared__ float hfin[NBB][32];
    __shared__ float hd[NBB][16];

    // ===== weight fragments: 2 tiles/wave =====
    bf16x8 wh[2][3], wl[2][3];
    f32x4  bfr[2];
    int    offs[2];
    if (wid < 8){
        #pragma unroll
        for (int tt = 0; tt < 2; ++tt){
            const int Tt = 2*wid + tt;
            const int g = Tt >> 2, rb = Tt & 3;
            const float s = (g == 2) ? K2f : K1f;
            offs[tt] = 64*g + 16*rb;
            const int r = offs[tt] + bb;
            make_frags_s(&W_ih1[r*32 +      8*kg], s, wh[tt][0], wl[tt][0]);
            make_frags_s(&W_hh1[r*64 +      8*kg], s, wh[tt][1], wl[tt][1]);
            make_frags_s(&W_hh1[r*64 + 32 + 8*kg], s, wh[tt][2], wl[tt][2]);
            #pragma unroll
            for (int q = 0; q < 4; ++q){
                const int row = offs[tt] + 4*kg + q;
                bfr[tt][q] = s * (b_ih1[row] + b_hh1[row]);
            }
        }
    } else {
        const int j = wid - 8;
        #pragma unroll
        for (int tt = 0; tt < 2; ++tt){
            const int St = 2*j + tt;
            const int g = St >> 1, rb = St & 1;
            const float s = (g == 2) ? K2f : K1f;
            offs[tt] = 32*g + 16*rb;
            const int r = offs[tt] + bb;
            make_frags_s(&W_ih2[r*64 +      8*kg], s, wh[tt][0], wl[tt][0]);
            make_frags_s(&W_ih2[r*64 + 32 + 8*kg], s, wh[tt][1], wl[tt][1]);
            make_frags_s(&W_hh2[r*32 +      8*kg], s, wh[tt][2], wl[tt][2]);
            #pragma unroll
            for (int q = 0; q < 4; ++q){
                const int row = offs[tt] + 4*kg + q;
                bfr[tt][q] = s * (b_ih2[row] + b_hh2[row]);
            }
        }
    }

    // ===== combine ownership: r9-style scalar stride-1 (conflict-free banks) =====
    // L1-combine (tid<512, P2): batch cb=tid>>5, units uu, uu+32 (uu=tid&31)
    const int cb = tid >> 5;
    const int uu = tid & 31;
    float c1a = 0.f, c1b = 0.f;
    // L2-combine + x (tid>=512, P1): lt=tid-512, batch cb2=lt>>4, units v, v+16
    const int lt  = tid & 255;
    const int cb2 = lt >> 4;
    const int v   = lt & 15;
    float c2a = 0.f, c2b = 0.f;
    const int xf = v * 2;
    const size_t xbase = (size_t)(b0 + cb2) * (T_*F_) + xf;
    float2 xc = make_float2(0.f, 0.f);

    // ===== init: zero images, stage x(0), preload x(1) =====
    for (int i = tid; i < 2*NBB*IMW; i += TPB){
        (&i1h[0][0][0])[i] = 0; (&i1l[0][0][0])[i] = 0;
        (&i2h[0][0][0])[i] = 0; (&i2l[0][0][0])[i] = 0;
    }
    __syncthreads();
    if (wid >= 8){
        float2 x0 = *(const float2*)&x[xbase];
        unsigned short hh, hl;
        bf16_split(x0.x, hh, hl); i1h[0][cb2][xf]   = hh; i1l[0][cb2][xf]   = hl;
        bf16_split(x0.y, hh, hl); i1h[0][cb2][xf+1] = hh; i1l[0][cb2][xf+1] = hl;
        xc = *(const float2*)&x[xbase + F_];
    }
    __syncthreads();

    // ===== main loop (r13 schedule, r16 distribution) =====
    // P1(t): L1-MFMA(t)->pre1 [w0-7]  |  L2-combine(t-2)->i2[nxt] + x(t+1)->i1[nxt] [w8-11]
    // P2(t): L1-combine(t)->i1[nxt],i2[cur] [w0-7]  |  L2-MFMA(t-1) from i2[nxt]->pre2 [w8-11]
    for (int t = 0; t <= T_ + 1; ++t){
        const int cur = t & 1, nxt = cur ^ 1;

        // ---------- P1 ----------
        if (wid < 8){
            if (t < T_){
                const unsigned short* ph = &i1h[cur][0][0] + bb*IMW + 8*kg;
                const unsigned short* pl = &i1l[cur][0][0] + bb*IMW + 8*kg;
                bf16x8 vh[3], vl[3];
                #pragma unroll
                for (int kb = 0; kb < 3; ++kb){
                    vh[kb] = *(const bf16x8*)(ph + 32*kb);
                    vl[kb] = *(const bf16x8*)(pl + 32*kb);
                }
                __builtin_amdgcn_s_setprio(1);
                f32x4 a0 = bfr[0], a1 = bfr[1];
                #pragma unroll
                for (int kb = 0; kb < 3; ++kb){
                    a0 = MFMA(wh[0][kb], vh[kb], a0);
                    a1 = MFMA(wh[1][kb], vh[kb], a1);
                }
                #pragma unroll
                for (int kb = 0; kb < 3; ++kb){
                    a0 = MFMA(wl[0][kb], vh[kb], a0);
                    a1 = MFMA(wl[1][kb], vh[kb], a1);
                }
                #pragma unroll
                for (int kb = 0; kb < 3; ++kb){
                    a0 = MFMA(wh[0][kb], vl[kb], a0);
                    a1 = MFMA(wh[1][kb], vl[kb], a1);
                }
                __builtin_amdgcn_s_setprio(0);
                *(f32x4*)&pre1[bb*PR1 + offs[0] + 4*kg] = a0;
                *(f32x4*)&pre1[bb*PR1 + offs[1] + 4*kg] = a1;
            }
        } else {
            const int m = t - 2;
            if (m >= 0 && m < T_){
                const float* p = &pre2[cb2*PR2];
                // scalar stride-1 reads: bank = 4*cb2 + v -> near-uniform spread
                const float h0 = unit_combine(p[v],      p[32 + v],      p[64 + v],      p[96 + v],      c2a);
                const float h1 = unit_combine(p[16 + v], p[48 + v],      p[80 + v],      p[112 + v],     c2b);
                unsigned short h0h, h0l, h1h, h1l;
                bf16_split(h0, h0h, h0l); bf16_split(h1, h1h, h1l);
                i2h[nxt][cb2][64 + v]  = h0h;  i2l[nxt][cb2][64 + v]  = h0l;
                i2h[nxt][cb2][80 + v]  = h1h;  i2l[nxt][cb2][80 + v]  = h1l;
                if (m == T_ - 1){ hfin[cb2][v] = h0; hfin[cb2][v + 16] = h1; }
            }
            if (t + 1 < T_){
                unsigned short hh, hl;
                bf16_split(xc.x, hh, hl);
                const unsigned w0h = hh, w0l = hl;
                bf16_split(xc.y, hh, hl);
                *(unsigned*)&i1h[nxt][cb2][xf] = w0h | ((unsigned)hh << 16);
                *(unsigned*)&i1l[nxt][cb2][xf] = w0l | ((unsigned)hl << 16);
                const int tn = (t + 2 < T_) ? t + 2 : T_ - 1;
                xc = *(const float2*)&x[xbase + (size_t)tn * F_];
            }
        }
        step_barrier();

        // ---------- P2 ----------
        if (wid < 8){
            if (t < T_){
                const float* p = &pre1[cb*PR1];
                // scalar stride-1 reads: bank = 4*cb + uu -> 32-bank spread, 2-way = free
                const float h0 = unit_combine(p[uu],      p[64 + uu],  p[128 + uu], p[192 + uu], c1a);
                const float h1 = unit_combine(p[32 + uu], p[96 + uu],  p[160 + uu], p[224 + uu], c1b);
                unsigned short h0h, h0l, h1h, h1l;
                bf16_split(h0, h0h, h0l); bf16_split(h1, h1h, h1l);
                // h1(t): units uu, uu+32
                i1h[nxt][cb][32 + uu] = h0h;  i1l[nxt][cb][32 + uu] = h0l;
                i1h[nxt][cb][64 + uu] = h1h;  i1l[nxt][cb][64 + uu] = h1l;
                i2h[cur][cb][uu]      = h0h;  i2l[cur][cb][uu]      = h0l;
                i2h[cur][cb][32 + uu] = h1h;  i2l[cur][cb][32 + uu] = h1l;
            }
        } else {
            const int k = t - 1;
            if (k >= 0 && k < T_){
                // i2[nxt] = [h1(k) | h2(k-1)]
                const unsigned short* ph = &i2h[nxt][0][0] + bb*IMW + 8*kg;
                const unsigned short* pl = &i2l[nxt][0][0] + bb*IMW + 8*kg;
                bf16x8 vh[3], vl[3];
                #pragma unroll
                for (int kb = 0; kb < 3; ++kb){
                    vh[kb] = *(const bf16x8*)(ph + 32*kb);
                    vl[kb] = *(const bf16x8*)(pl + 32*kb);
                }
                __builtin_amdgcn_s_setprio(1);
                f32x4 a0 = bfr[0], a1 = bfr[1];
                #pragma unroll
                for (int kb = 0; kb < 3; ++kb){
                    a0 = MFMA(wh[0][kb], vh[kb], a0);
                    a1 = MFMA(wh[1][kb], vh[kb], a1);
                }
                #pragma unroll
                for (int kb = 0; kb < 3; ++kb){
                    a0 = MFMA(wl[0][kb], vh[kb], a0);
                    a1 = MFMA(wl[1][kb], vh[kb], a1);
                }
                #pragma unroll
                for (int kb = 0; kb < 3; ++kb){
                    a0 = MFMA(wh[0][kb], vl[kb], a0);
                    a1 = MFMA(wh[1][kb], vl[kb], a1);
                }
                __builtin_amdgcn_s_setprio(0);
                *(f32x4*)&pre2[bb*PR2 + offs[0] + 4*kg] = a0;
                *(f32x4*)&pre2[bb*PR2 + offs[1] + 4*kg] = a1;
            }
        }
        step_barrier();
    }

    __syncthreads();
    // ===== head: fc1(16)+relu, fc2(1) =====
    if (tid < NBB * 16){
        const int b = tid >> 4, j2 = tid & 15;
        float a = b_fc1[j2];
        #pragma unroll
        for (int kk = 0; kk < 32; ++kk) a = fmaf(W_fc1[j2*32 + kk], hfin[b][kk], a);
        hd[b][j2] = fmaxf(a, 0.f);
    }
    __syncthreads();
    if (tid < NBB){
        float a = b_fc2[0];
        #pragma unroll
        for (int kk = 0; kk < 16; ++kk) a = fmaf(W_fc2[kk], hd[tid][kk], a);
        out[b0 + tid] = a;
    }
}

extern "C" void kernel_launch(void* const* d_in, const int* in_sizes, int n_in,
                              void* d_out, int out_size, void* d_ws, size_t ws_size,
                              hipStream_t stream) {
    const float* x     = (const float*)d_in[0];
    const float* W_ih1 = (const float*)d_in[1];
    const float* W_hh1 = (const float*)d_in[2];
    const float* b_ih1 = (const float*)d_in[3];
    const float* b_hh1 = (const float*)d_in[4];
    const float* W_ih2 = (const float*)d_in[5];
    const float* W_hh2 = (const float*)d_in[6];
    const float* b_ih2 = (const float*)d_in[7];
    const float* b_hh2 = (const float*)d_in[8];
    const float* W_fc1 = (const float*)d_in[9];
    const float* b_fc1 = (const float*)d_in[10];
    const float* W_fc2 = (const float*)d_in[11];
    const float* b_fc2 = (const float*)d_in[12];
    float* out = (float*)d_out;

    const int B = in_sizes[0] / (T_ * F_);   // 4096
    dim3 grid(B / NBB), block(TPB);          // 256 blocks, 1/CU, 12 waves
    hipLaunchKernelGGL(lstm_mfma, grid, block, 0, stream,
                       x, W_ih1, W_hh1, b_ih1, b_hh1,
                       W_ih2, W_hh2, b_ih2, b_hh2,
                       W_fc1, b_fc1, W_fc2, b_fc2, out);
}

// Round 18
// 244.771 us; speedup vs baseline: 1.2135x; 1.2135x over previous
//
#include <hip/hip_runtime.h>

#define T_   256
#define F_   32
#define NBB  16     // full 16-wide fragments
#define TPB  768    // 12 waves: 0-7 L1-role (2 tiles), 8-11 L2-role (2 tiles)
#define IMW  104
#define XLW  40     // x-lo row pitch (ushorts, 80B = 16B-aligned)
#define PR1  260    // pre1 row stride (f32), 16B-aligned
#define PR2  132

typedef __attribute__((ext_vector_type(8))) short bf16x8;
typedef __attribute__((ext_vector_type(4))) float f32x4;

#define K1f  (-1.44269504f)   // -log2(e)   : sigmoid gates
#define K2f  (-2.88539008f)   // -2*log2(e) : tanh gate & tanh(c)

__device__ __forceinline__ unsigned short bf16_rne(float x){
    unsigned u = __float_as_uint(x);
    u += 0x7FFF + ((u >> 16) & 1);
    return (unsigned short)(u >> 16);
}
__device__ __forceinline__ void bf16_split(float x, unsigned short& h, unsigned short& l){
    h = bf16_rne(x);
    float xr = __uint_as_float(((unsigned)h) << 16);
    l = bf16_rne(x - xr);
}
__device__ __forceinline__ void make_frags_s(const float* __restrict__ p8, float s,
                                             bf16x8& fh, bf16x8& fl){
    #pragma unroll
    for (int e = 0; e < 8; ++e){
        unsigned short h, l; bf16_split(s * p8[e], h, l);
        fh[e] = (short)h; fl[e] = (short)l;
    }
}
__device__ __forceinline__ float sigm_pre(float p){   // p = -log2e*x
    return __builtin_amdgcn_rcpf(1.f + __builtin_amdgcn_exp2f(p));
}
__device__ __forceinline__ float tanh_pre(float p){   // p = -2log2e*x
    return fmaf(2.f, __builtin_amdgcn_rcpf(1.f + __builtin_amdgcn_exp2f(p)), -1.f);
}
__device__ __forceinline__ float unit_combine(float gi, float gf, float gg, float go, float& c){
    const float i_ = sigm_pre(gi);
    const float f_ = sigm_pre(gf);
    const float g_ = tanh_pre(gg);
    const float o_ = sigm_pre(go);
    c = fmaf(f_, c, i_ * g_);
    return o_ * tanh_pre(K2f * c);
}

#define MFMA(A,B,C) __builtin_amdgcn_mfma_f32_16x16x32_bf16((A),(B),(C),0,0,0)

// LDS-visibility barrier WITHOUT vmcnt drain (x-loads stay in flight).
__device__ __forceinline__ void step_barrier(){
    asm volatile("s_waitcnt lgkmcnt(0)" ::: "memory");
    __builtin_amdgcn_s_barrier();
}

// (768,3): 12 waves = 3/SIMD; r16 measured VGPR=64 + AGPR weights, no spill.
__global__ __launch_bounds__(TPB, 3) void lstm_mfma(
    const float* __restrict__ x,      // [4096,256,32]
    const float* __restrict__ W_ih1,  // [256,32]
    const float* __restrict__ W_hh1,  // [256,64]
    const float* __restrict__ b_ih1,  // [256]
    const float* __restrict__ b_hh1,  // [256]
    const float* __restrict__ W_ih2,  // [128,64]
    const float* __restrict__ W_hh2,  // [128,32]
    const float* __restrict__ b_ih2,  // [128]
    const float* __restrict__ b_hh2,  // [128]
    const float* __restrict__ W_fc1,  // [16,32]
    const float* __restrict__ b_fc1,  // [16]
    const float* __restrict__ W_fc2,  // [1,16]
    const float* __restrict__ b_fc2,  // [1]
    float* __restrict__ out)          // [4096]
{
    const int tid  = threadIdx.x;
    const int lane = tid & 63;
    const int wid  = tid >> 6;        // 0..11
    const int bb   = lane & 15;       // fragment col = batch
    const int kg   = (lane >> 4) & 3; // k-group of 8
    const int b0   = blockIdx.x * NBB;

    // hi images only for h; x keeps a lo sidecar (W & x retain full precision,
    // h is plain bf16 -- error budget: ~1-3e-4 vs 9e-4 threshold)
    __shared__ __align__(16) unsigned short i1h[2][NBB][IMW];   // [x(32)|h1(64)] hi
    __shared__ __align__(16) unsigned short x1l[2][NBB][XLW];   // x lo
    __shared__ __align__(16) unsigned short i2h[2][NBB][IMW];   // [h1(64)|h2(32)] hi
    __shared__ __align__(16) float pre1[NBB * PR1];
    __shared__ __align__(16) float pre2[NBB * PR2];
    __shared__ float hfin[NBB][32];
    __shared__ float hd[NBB][16];

    // ===== weight fragments: 2 tiles/wave (hi+lo, pre-scaled) =====
    bf16x8 wh[2][3], wl[2][3];
    f32x4  bfr[2];
    int    offs[2];
    if (wid < 8){
        #pragma unroll
        for (int tt = 0; tt < 2; ++tt){
            const int Tt = 2*wid + tt;
            const int g = Tt >> 2, rb = Tt & 3;
            const float s = (g == 2) ? K2f : K1f;
            offs[tt] = 64*g + 16*rb;
            const int r = offs[tt] + bb;
            make_frags_s(&W_ih1[r*32 +      8*kg], s, wh[tt][0], wl[tt][0]);
            make_frags_s(&W_hh1[r*64 +      8*kg], s, wh[tt][1], wl[tt][1]);
            make_frags_s(&W_hh1[r*64 + 32 + 8*kg], s, wh[tt][2], wl[tt][2]);
            #pragma unroll
            for (int q = 0; q < 4; ++q){
                const int row = offs[tt] + 4*kg + q;
                bfr[tt][q] = s * (b_ih1[row] + b_hh1[row]);
            }
        }
    } else {
        const int j = wid - 8;
        #pragma unroll
        for (int tt = 0; tt < 2; ++tt){
            const int St = 2*j + tt;
            const int g = St >> 1, rb = St & 1;
            const float s = (g == 2) ? K2f : K1f;
            offs[tt] = 32*g + 16*rb;
            const int r = offs[tt] + bb;
            make_frags_s(&W_ih2[r*64 +      8*kg], s, wh[tt][0], wl[tt][0]);
            make_frags_s(&W_ih2[r*64 + 32 + 8*kg], s, wh[tt][1], wl[tt][1]);
            make_frags_s(&W_hh2[r*32 +      8*kg], s, wh[tt][2], wl[tt][2]);
            #pragma unroll
            for (int q = 0; q < 4; ++q){
                const int row = offs[tt] + 4*kg + q;
                bfr[tt][q] = s * (b_ih2[row] + b_hh2[row]);
            }
        }
    }

    // ===== combine ownership (r16 float2 mapping -- measured best) =====
    const int cb = tid >> 5;          // L1-combine: batch, units u0,u0+1
    const int u0 = (tid & 31) * 2;
    float c1a = 0.f, c1b = 0.f;
    const int lt  = tid & 255;        // L2-combine + x (waves 8-11)
    const int cb2 = lt >> 4;
    const int v0  = (lt & 15) * 2;
    float c2a = 0.f, c2b = 0.f;
    const int xf = (lt & 15) * 2;
    const size_t xbase = (size_t)(b0 + cb2) * (T_*F_) + xf;
    float2 xc = make_float2(0.f, 0.f);

    // ===== init: zero images, stage x(0), preload x(1) =====
    for (int i = tid; i < 2*NBB*IMW; i += TPB){
        (&i1h[0][0][0])[i] = 0; (&i2h[0][0][0])[i] = 0;
    }
    for (int i = tid; i < 2*NBB*XLW; i += TPB) (&x1l[0][0][0])[i] = 0;
    __syncthreads();
    if (wid >= 8){
        float2 x0 = *(const float2*)&x[xbase];
        unsigned short h0h, h0l, h1h, h1l;
        bf16_split(x0.x, h0h, h0l); bf16_split(x0.y, h1h, h1l);
        *(unsigned*)&i1h[0][cb2][xf] = (unsigned)h0h | ((unsigned)h1h << 16);
        *(unsigned*)&x1l[0][cb2][xf] = (unsigned)h0l | ((unsigned)h1l << 16);
        xc = *(const float2*)&x[xbase + F_];
    }
    __syncthreads();

    // ===== main loop (r16 schedule) =====
    // P1(t): L1-MFMA(t)->pre1 [w0-7]  |  L2-combine(t-2)->i2h[nxt] + x(t+1) [w8-11]
    // P2(t): L1-combine(t)->i1h[nxt],i2h[cur] [w0-7]  |  L2-MFMA(t-1)->pre2 [w8-11]
    for (int t = 0; t <= T_ + 1; ++t){
        const int cur = t & 1, nxt = cur ^ 1;

        // ---------- P1 ----------
        if (wid < 8){
            if (t < T_){
                const unsigned short* ph = &i1h[cur][0][0] + bb*IMW + 8*kg;
                bf16x8 vh[3];
                #pragma unroll
                for (int kb = 0; kb < 3; ++kb)
                    vh[kb] = *(const bf16x8*)(ph + 32*kb);
                const bf16x8 vl0 = *(const bf16x8*)&x1l[cur][bb][8*kg];
                __builtin_amdgcn_s_setprio(1);
                f32x4 a0 = bfr[0], a1 = bfr[1];
                #pragma unroll
                for (int kb = 0; kb < 3; ++kb){
                    a0 = MFMA(wh[0][kb], vh[kb], a0);
                    a1 = MFMA(wh[1][kb], vh[kb], a1);
                }
                #pragma unroll
                for (int kb = 0; kb < 3; ++kb){
                    a0 = MFMA(wl[0][kb], vh[kb], a0);
                    a1 = MFMA(wl[1][kb], vh[kb], a1);
                }
                a0 = MFMA(wh[0][0], vl0, a0);   // x-lo contribution (k 0..31 only)
                a1 = MFMA(wh[1][0], vl0, a1);
                __builtin_amdgcn_s_setprio(0);
                *(f32x4*)&pre1[bb*PR1 + offs[0] + 4*kg] = a0;
                *(f32x4*)&pre1[bb*PR1 + offs[1] + 4*kg] = a1;
            }
        } else {
            const int m = t - 2;
            if (m >= 0 && m < T_){
                const float* p = &pre2[cb2*PR2];
                const float2 gi = *(const float2*)&p[     v0];
                const float2 gf = *(const float2*)&p[32 + v0];
                const float2 gg = *(const float2*)&p[64 + v0];
                const float2 go = *(const float2*)&p[96 + v0];
                const float h0 = unit_combine(gi.x, gf.x, gg.x, go.x, c2a);
                const float h1 = unit_combine(gi.y, gf.y, gg.y, go.y, c2b);
                *(unsigned*)&i2h[nxt][cb2][64 + v0] =
                    (unsigned)bf16_rne(h0) | ((unsigned)bf16_rne(h1) << 16);
                if (m == T_ - 1){ hfin[cb2][v0] = h0; hfin[cb2][v0+1] = h1; }
            }
            if (t + 1 < T_){
                unsigned short h0h, h0l, h1h, h1l;
                bf16_split(xc.x, h0h, h0l); bf16_split(xc.y, h1h, h1l);
                *(unsigned*)&i1h[nxt][cb2][xf] = (unsigned)h0h | ((unsigned)h1h << 16);
                *(unsigned*)&x1l[nxt][cb2][xf] = (unsigned)h0l | ((unsigned)h1l << 16);
                const int tn = (t + 2 < T_) ? t + 2 : T_ - 1;
                xc = *(const float2*)&x[xbase + (size_t)tn * F_];
            }
        }
        step_barrier();

        // ---------- P2 ----------
        if (wid < 8){
            if (t < T_){
                const float* p = &pre1[cb*PR1];
                const float2 gi = *(const float2*)&p[      u0];
                const float2 gf = *(const float2*)&p[ 64 + u0];
                const float2 gg = *(const float2*)&p[128 + u0];
                const float2 go = *(const float2*)&p[192 + u0];
                const float h0 = unit_combine(gi.x, gf.x, gg.x, go.x, c1a);
                const float h1 = unit_combine(gi.y, gf.y, gg.y, go.y, c1b);
                const unsigned wh_ =
                    (unsigned)bf16_rne(h0) | ((unsigned)bf16_rne(h1) << 16);
                *(unsigned*)&i1h[nxt][cb][32 + u0] = wh_;   // h1(t) for L1-MFMA(t+1)
                *(unsigned*)&i2h[cur][cb][u0]      = wh_;   // h1(t) for L2-MFMA(t)
            }
        } else {
            const int k = t - 1;
            if (k >= 0 && k < T_){
                // i2h[nxt] = [h1(k) | h2(k-1)]
                const unsigned short* ph = &i2h[nxt][0][0] + bb*IMW + 8*kg;
                bf16x8 vh[3];
                #pragma unroll
                for (int kb = 0; kb < 3; ++kb)
                    vh[kb] = *(const bf16x8*)(ph + 32*kb);
                __builtin_amdgcn_s_setprio(1);
                f32x4 a0 = bfr[0], a1 = bfr[1];
                #pragma unroll
                for (int kb = 0; kb < 3; ++kb){
                    a0 = MFMA(wh[0][kb], vh[kb], a0);
                    a1 = MFMA(wh[1][kb], vh[kb], a1);
                }
                #pragma unroll
                for (int kb = 0; kb < 3; ++kb){
                    a0 = MFMA(wl[0][kb], vh[kb], a0);
                    a1 = MFMA(wl[1][kb], vh[kb], a1);
                }
                __builtin_amdgcn_s_setprio(0);
                *(f32x4*)&pre2[bb*PR2 + offs[0] + 4*kg] = a0;
                *(f32x4*)&pre2[bb*PR2 + offs[1] + 4*kg] = a1;
            }
        }
        step_barrier();
    }

    __syncthreads();
    // ===== head: fc1(16)+relu, fc2(1) =====
    if (tid < NBB * 16){
        const int b = tid >> 4, j2 = tid & 15;
        float a = b_fc1[j2];
        #pragma unroll
        for (int kk = 0; kk < 32; ++kk) a = fmaf(W_fc1[j2*32 + kk], hfin[b][kk], a);
        hd[b][j2] = fmaxf(a, 0.f);
    }
    __syncthreads();
    if (tid < NBB){
        float a = b_fc2[0];
        #pragma unroll
        for (int kk = 0; kk < 16; ++kk) a = fmaf(W_fc2[kk], hd[tid][kk], a);
        out[b0 + tid] = a;
    }
}

extern "C" void kernel_launch(void* const* d_in, const int* in_sizes, int n_in,
                              void* d_out, int out_size, void* d_ws, size_t ws_size,
                              hipStream_t stream) {
    const float* x     = (const float*)d_in[0];
    const float* W_ih1 = (const float*)d_in[1];
    const float* W_hh1 = (const float*)d_in[2];
    const float* b_ih1 = (const float*)d_in[3];
    const float* b_hh1 = (const float*)d_in[4];
    const float* W_ih2 = (const float*)d_in[5];
    const float* W_hh2 = (const float*)d_in[6];
    const float* b_ih2 = (const float*)d_in[7];
    const float* b_hh2 = (const float*)d_in[8];
    const float* W_fc1 = (const float*)d_in[9];
    const float* b_fc1 = (const float*)d_in[10];
    const float* W_fc2 = (const float*)d_in[11];
    const float* b_fc2 = (const float*)d_in[12];
    float* out = (float*)d_out;

    const int B = in_sizes[0] / (T_ * F_);   // 4096
    dim3 grid(B / NBB), block(TPB);          // 256 blocks, 1/CU, 12 waves
    hipLaunchKernelGGL(lstm_mfma, grid, block, 0, stream,
                       x, W_ih1, W_hh1, b_ih1, b_hh1,
                       W_ih2, W_hh2, b_ih2, b_hh2,
                       W_fc1, b_fc1, W_fc2, b_fc2, out);
}